// Round 6
// baseline (3234.925 us; speedup 1.0000x reference)
//
#include <hip/hip_runtime.h>
#include <hip/hip_bf16.h>

// Two-layer tanh RNN, B=32 T=512 I=512 H=1024, fp32 in/out, bf16 MFMA compute.
// Fused persistent kernel, 128 WGs x 128 thr (WGs 0-63 = L0, 64-127 = L1).
// Round-6: same data-embedded sync design as round 5, with the prep_kernel
// x-conversion bound FIXED (2,097,152 float4s, not 4,194,304 -- round 5 read
// 32MB past x and stomped h1buf, causing the abort).
// Design: tanh outputs lie in [-1,1] -> bf16 bit14 never set; poison 0x7F80
// has bit14 set. Per-step h slots are pre-poisoned; consumers poll the data
// itself and re-load until poison clears. Producers store-and-go: no vmcnt
// ack, no flags -- removes 2 of the 3 serial L3 round trips per step that
// paced rounds 1-4. Slots are write-once => re-loads idempotent.

#define B_ 32
#define T_ 512
#define I_ 512
#define H_ 1024

typedef __attribute__((ext_vector_type(8))) short short8;
typedef __attribute__((ext_vector_type(4))) float float4v;

// ---- workspace layout (bytes) ----
#define OFF_XBF   0ull            // x_bf : B*T*I bf16 = 16,777,216
#define OFF_H1    16777216ull     // h1  : (T+1)*B*H bf16 = 33,619,968
#define OFF_H2    50397184ull     // h2  : FULL: (T+1) slots; else ping-pong
#define OFF_FLAGS 50528256ull     // flags: 128 * 64 B (fallback only)
#define NEED_FULL 84017152ull

#define POIS 0x7F807F80u

#define WAIT_VM0() asm volatile("s_waitcnt vmcnt(0)" ::: "memory")
#define CFENCE()   asm volatile("" ::: "memory")

// One 16B L2-bypassing load (agent-coherent), no implicit wait.
#define LDF(f, base, O) \
  asm volatile("global_load_dwordx4 %0, %1, off offset:%2 sc1" \
               : "=v"(f) : "v"(base), "n"(O) : "memory")

#define LD8(F, S, BASE, OB) \
  LDF(F[S+0], BASE, OB+0);   LDF(F[S+1], BASE, OB+64); \
  LDF(F[S+2], BASE, OB+128); LDF(F[S+3], BASE, OB+192); \
  LDF(F[S+4], BASE, OB+256); LDF(F[S+5], BASE, OB+320); \
  LDF(F[S+6], BASE, OB+384); LDF(F[S+7], BASE, OB+448)

// Staged wait; register ties stop the scheduler hoisting consumers above it.
#define VMW8(N, F, S) \
  asm volatile("s_waitcnt vmcnt(" #N ")" \
               : "+v"(F[S+0]), "+v"(F[S+1]), "+v"(F[S+2]), "+v"(F[S+3]), \
                 "+v"(F[S+4]), "+v"(F[S+5]), "+v"(F[S+6]), "+v"(F[S+7]))

// Fresh-data check: or-reduce all 32 dwords of the 8 fragments; fresh bf16
// halves (tanh range, |v|<=1.0=0x3F80) never set bit14; poison always does.
__device__ __forceinline__ bool any8_stale(const short8* F, int S) {
  union { short8 s; unsigned u[4]; } x;
  unsigned o = 0u;
#pragma unroll
  for (int i = 0; i < 8; ++i) { x.s = F[S+i]; o |= x.u[0] | x.u[1] | x.u[2] | x.u[3]; }
  return (o & 0x40004000u) != 0u;
}

// Poll-retry: while any lane sees poison, re-load all 8 (write-once slots ->
// idempotent) and re-check. Must follow a VMW8 that tied these regs.
#define POLL8(F, S, BASE, OB) \
  do { \
    while (__any((int)any8_stale(F, S))) { \
      __builtin_amdgcn_s_sleep(1); \
      LD8(F, S, BASE, OB); \
      asm volatile("s_waitcnt vmcnt(0)" \
                   : "+v"(F[S+0]), "+v"(F[S+1]), "+v"(F[S+2]), "+v"(F[S+3]), \
                     "+v"(F[S+4]), "+v"(F[S+5]), "+v"(F[S+6]), "+v"(F[S+7])); \
    } \
  } while (0)

#define MFMA_B(acc, f, kb) \
  acc = __builtin_amdgcn_mfma_f32_16x16x32_bf16( \
      f, *reinterpret_cast<const short8*>(ldsW + (kb) * 512 + lofs), acc, 0, 0, 0)

#define MF8(F, S, KB) \
  MFMA_B(accA, F[S+0], KB+0); MFMA_B(accB, F[S+1], KB+1); \
  MFMA_B(accA, F[S+2], KB+2); MFMA_B(accB, F[S+3], KB+3); \
  MFMA_B(accA, F[S+4], KB+4); MFMA_B(accB, F[S+5], KB+5); \
  MFMA_B(accA, F[S+6], KB+6); MFMA_B(accB, F[S+7], KB+7)

// tanh via exp2+rcp: output strictly in [-1,1] (poison-scheme requirement).
__device__ __forceinline__ float fast_tanh(float x) {
  float z = fminf(2.885390081777927f * x, 60.0f);
  float e = __builtin_amdgcn_exp2f(z);
  return 1.0f - 2.0f * __builtin_amdgcn_rcpf(e + 1.0f);
}

// Fallback-path flag wait (round-4 style), L1 self-chain only.
__device__ __forceinline__ void wait_flags(unsigned* fbase, int lane, int wid, unsigned s) {
  unsigned* p = fbase + (((unsigned)lane << 1) + wid) * 16;
  while (__hip_atomic_load(p, __ATOMIC_RELAXED, __HIP_MEMORY_SCOPE_AGENT) < s)
    __builtin_amdgcn_s_sleep(1);
  CFENCE();
}

template<bool FULL>
__global__ __launch_bounds__(128)
void rnn_fused(const float* __restrict__ Wih0, const float* __restrict__ Whh0,
               const float* __restrict__ bih0, const float* __restrict__ bhh0,
               const float* __restrict__ Wih1, const float* __restrict__ Whh1,
               const float* __restrict__ bih1, const float* __restrict__ bhh1,
               const __hip_bfloat16* __restrict__ x_bf,
               __hip_bfloat16* __restrict__ h1buf,
               __hip_bfloat16* __restrict__ h2buf,
               float* __restrict__ out,
               unsigned* __restrict__ flags)
{
  __shared__ unsigned short ldsW[16 * 2048];   // 64 KB (L0 uses 48 KB)
  const int tid  = threadIdx.x;
  const int wgid = blockIdx.x;
  const bool isL1 = (wgid >= 64);
  const int wg   = isL1 ? wgid - 64 : wgid;    // output cols wg*16..+16
  const int KIN  = isL1 ? H_ : I_;
  const int KTOT = KIN + H_;
  const float* Wih = isL1 ? Wih1 : Wih0;
  const float* Whh = isL1 ? Whh1 : Whh0;

  // Stage weight slice into LDS in MFMA B-fragment order (once).
  for (int idx = tid; idx < 16 * KTOT; idx += 128) {
    int c = idx / KTOT;
    int k = idx - c * KTOT;
    float w = (k < KIN) ? Wih[(size_t)(wg * 16 + c) * KIN + k]
                        : Whh[(size_t)(wg * 16 + c) * H_ + (k - KIN)];
    __hip_bfloat16 hb = __float2bfloat16(w);
    int pos = ((k >> 5) * 64 + ((k >> 3) & 3) * 16 + c) * 8 + (k & 7);
    ldsW[pos] = *reinterpret_cast<unsigned short*>(&hb);
  }

  const int lane  = tid & 63;
  const int wid   = tid >> 6;                    // batch rows wid*16..+16
  const int col   = wg * 16 + (lane & 15);
  const float biasv = isL1 ? (bih1[col] + bhh1[col]) : (bih0[col] + bhh0[col]);
  const int arow  = wid * 16 + (lane & 15);      // A-frag row (batch index)
  const int ksub  = ((lane >> 4) & 3) * 8;       // A-frag k sub-offset
  const int lofs  = lane * 8;                    // B-frag LDS elem offset
  const int rbase = wid * 16 + (lane >> 4) * 4;  // C-frag row base
  const int r0    = (lane & 1) ? 2 : 0;          // rows this lane stores
  const int colp  = col & ~1;

  unsigned* myflag = flags + (((unsigned)wg << 1) + wid) * 16;  // fallback only

  __syncthreads();   // weights staged

  if (!isL1) {
    // ================= layer 0 =================
    for (int s = 0; s < T_; ++s) {
      float4v accA = {biasv, biasv, biasv, biasv};
      float4v accB = {0.f, 0.f, 0.f, 0.f};
      const __hip_bfloat16* a0 = x_bf + (size_t)arow * (T_ * I_) + (size_t)s * I_ + ksub;
#pragma unroll
      for (int kb = 0; kb < 16; ++kb) {
        short8 av = *reinterpret_cast<const short8*>(a0 + kb * 32);
        MFMA_B(accA, av, kb);
      }
      const __hip_bfloat16* a1 = h1buf + (size_t)s * (B_ * H_) + (size_t)arow * H_ + ksub;
      short8 g[32];
      LD8(g, 0, a1, 0);  LD8(g, 8, a1, 512);  LD8(g, 16, a1, 1024);  LD8(g, 24, a1, 1536);
      VMW8(24, g, 0);   POLL8(g, 0, a1, 0);     MF8(g, 0, 16);
      VMW8(16, g, 8);   POLL8(g, 8, a1, 512);   MF8(g, 8, 24);
      VMW8(8,  g, 16);  POLL8(g, 16, a1, 1024); MF8(g, 16, 32);
      VMW8(0,  g, 24);  POLL8(g, 24, a1, 1536); MF8(g, 24, 40);

      __hip_bfloat16* hd = h1buf + (size_t)(s + 1) * (B_ * H_);
      float hv[4];
#pragma unroll
      for (int r = 0; r < 4; ++r) hv[r] = fast_tanh(accA[r] + accB[r]);
#pragma unroll
      for (int r = 0; r < 4; ++r) {
        float other = __shfl_xor(hv[r], 1, 64);
        float lo = (lane & 1) ? other : hv[r];
        float hi = (lane & 1) ? hv[r] : other;
        if (r == r0 || r == r0 + 1) {
          __hip_bfloat16 l16 = __float2bfloat16(lo), h16 = __float2bfloat16(hi);
          unsigned pk = (unsigned)*(unsigned short*)&l16 | ((unsigned)*(unsigned short*)&h16 << 16);
          unsigned* dst = (unsigned*)(hd + (size_t)(rbase + r) * H_ + colp);
          __hip_atomic_store(dst, pk, __ATOMIC_RELAXED, __HIP_MEMORY_SCOPE_AGENT);
        }
      }
      // store-and-go: consumers poll the data itself.
    }
  } else {
    // ================= layer 1 =================
    for (int t = 0; t < T_; ++t) {
      float4v accA = {biasv, biasv, biasv, biasv};
      float4v accB = {0.f, 0.f, 0.f, 0.f};
      const __hip_bfloat16* aA = h1buf + (size_t)(t + 1) * (B_ * H_) + (size_t)arow * H_ + ksub;
      const __hip_bfloat16* aB;
      if constexpr (FULL) {
        aB = h2buf + (size_t)t * (B_ * H_) + (size_t)arow * H_ + ksub;
      } else {
        if (t > 0) wait_flags(flags, lane, wid, (unsigned)t);
        aB = h2buf + (size_t)(t & 1) * (B_ * H_) + (size_t)arow * H_ + ksub;
      }
      short8 g[32], h[32];
      LD8(g, 0, aA, 0);  LD8(g, 8, aA, 512);  LD8(g, 16, aA, 1024);  LD8(g, 24, aA, 1536);
      VMW8(24, g, 0);   POLL8(g, 0, aA, 0);     MF8(g, 0, 0);    LD8(h, 0, aB, 0);
      VMW8(24, g, 8);   POLL8(g, 8, aA, 512);   MF8(g, 8, 8);    LD8(h, 8, aB, 512);
      VMW8(24, g, 16);  POLL8(g, 16, aA, 1024); MF8(g, 16, 16);  LD8(h, 16, aB, 1024);
      VMW8(24, g, 24);  POLL8(g, 24, aA, 1536); MF8(g, 24, 24);  LD8(h, 24, aB, 1536);
      VMW8(24, h, 0);   if constexpr (FULL) POLL8(h, 0, aB, 0);     MF8(h, 0, 32);
      VMW8(16, h, 8);   if constexpr (FULL) POLL8(h, 8, aB, 512);   MF8(h, 8, 40);
      VMW8(8,  h, 16);  if constexpr (FULL) POLL8(h, 16, aB, 1024); MF8(h, 16, 48);
      VMW8(0,  h, 24);  if constexpr (FULL) POLL8(h, 24, aB, 1536); MF8(h, 24, 56);

      __hip_bfloat16* hd = FULL ? h2buf + (size_t)(t + 1) * (B_ * H_)
                                : h2buf + (size_t)((t + 1) & 1) * (B_ * H_);
      float hv[4];
#pragma unroll
      for (int r = 0; r < 4; ++r) hv[r] = fast_tanh(accA[r] + accB[r]);
      float lov[4], hiv[4];
#pragma unroll
      for (int r = 0; r < 4; ++r) {
        float other = __shfl_xor(hv[r], 1, 64);
        lov[r] = (lane & 1) ? other : hv[r];
        hiv[r] = (lane & 1) ? hv[r] : other;
        if (r == r0 || r == r0 + 1) {
          __hip_bfloat16 l16 = __float2bfloat16(lov[r]), h16 = __float2bfloat16(hiv[r]);
          unsigned pk = (unsigned)*(unsigned short*)&l16 | ((unsigned)*(unsigned short*)&h16 << 16);
          unsigned* dst = (unsigned*)(hd + (size_t)(rbase + r) * H_ + colp);
          __hip_atomic_store(dst, pk, __ATOMIC_RELAXED, __HIP_MEMORY_SCOPE_AGENT);
        }
      }
      if constexpr (!FULL) {
        WAIT_VM0();
        if (lane == 0)
          __hip_atomic_store(myflag, (unsigned)(t + 1), __ATOMIC_RELAXED, __HIP_MEMORY_SCOPE_AGENT);
      }
      // fp32 outputs off the critical path.
#pragma unroll
      for (int r = 0; r < 4; ++r) {
        if (r == r0 || r == r0 + 1) {
          float2 f2; f2.x = lov[r]; f2.y = hiv[r];
          *(float2*)(out + (size_t)(rbase + r) * (T_ * H_) + (size_t)t * H_ + colp) = f2;
        }
      }
    }
  }
}

// Re-init every call (ws poisoned 0xAA by harness): x->bf16 (2,097,152 float4s
// -- EXACT bound, round 5's 2x overread was the abort); h1 slot0 zeros, slots
// 1..T POISON; h2 likewise (FULL) or ping-pong zeros + flags (fallback).
__global__ void prep_kernel(const float* __restrict__ x, unsigned long long* __restrict__ x64,
                            unsigned* __restrict__ h1, unsigned* __restrict__ h2,
                            unsigned* __restrict__ flags, int full)
{
  unsigned i = blockIdx.x * 256 + threadIdx.x;
  if (i < 2097152u) {                      // B*T*I/4 float4 elements
    const float4* x4 = (const float4*)x;
    float4 v = x4[i];
    __hip_bfloat16 b0 = __float2bfloat16(v.x), b1 = __float2bfloat16(v.y);
    __hip_bfloat16 b2 = __float2bfloat16(v.z), b3 = __float2bfloat16(v.w);
    unsigned long long r = (unsigned long long)*(unsigned short*)&b0
                         | ((unsigned long long)*(unsigned short*)&b1 << 16)
                         | ((unsigned long long)*(unsigned short*)&b2 << 32)
                         | ((unsigned long long)*(unsigned short*)&b3 << 48);
    x64[i] = r;
  }
  const unsigned NH = 513u * 16384u;   // dwords in a (T+1)-slot h buffer
  if (i < NH) {
    unsigned v = (i < 16384u) ? 0u : POIS;
    __hip_atomic_store(h1 + i, v, __ATOMIC_RELAXED, __HIP_MEMORY_SCOPE_AGENT);
    if (full)
      __hip_atomic_store(h2 + i, v, __ATOMIC_RELAXED, __HIP_MEMORY_SCOPE_AGENT);
  }
  if (!full) {
    if (i < 32768u) __hip_atomic_store(h2 + i, 0u, __ATOMIC_RELAXED, __HIP_MEMORY_SCOPE_AGENT);
    if (i < 2048u)  __hip_atomic_store(flags + i, 0u, __ATOMIC_RELAXED, __HIP_MEMORY_SCOPE_AGENT);
  }
}

extern "C" void kernel_launch(void* const* d_in, const int* in_sizes, int n_in,
                              void* d_out, int out_size, void* d_ws, size_t ws_size,
                              hipStream_t stream)
{
  const float* x    = (const float*)d_in[0];
  const float* Wih0 = (const float*)d_in[1];
  const float* Whh0 = (const float*)d_in[2];
  const float* bih0 = (const float*)d_in[3];
  const float* bhh0 = (const float*)d_in[4];
  const float* Wih1 = (const float*)d_in[5];
  const float* Whh1 = (const float*)d_in[6];
  const float* bih1 = (const float*)d_in[7];
  const float* bhh1 = (const float*)d_in[8];
  float* out = (float*)d_out;
  char* ws = (char*)d_ws;

  __hip_bfloat16* x_bf  = (__hip_bfloat16*)(ws + OFF_XBF);
  __hip_bfloat16* h1buf = (__hip_bfloat16*)(ws + OFF_H1);
  __hip_bfloat16* h2buf = (__hip_bfloat16*)(ws + OFF_H2);
  unsigned* flags = (unsigned*)(ws + OFF_FLAGS);

  const bool full = (ws_size >= NEED_FULL);

  // 513*16384 dwords = 8,404,992 -> 32832 blocks of 256 covers every range.
  prep_kernel<<<32832, 256, 0, stream>>>(x, (unsigned long long*)x_bf,
                                         (unsigned*)h1buf, (unsigned*)h2buf,
                                         flags, full ? 1 : 0);

  if (full)
    rnn_fused<true><<<128, 128, 0, stream>>>(Wih0, Whh0, bih0, bhh0,
                                             Wih1, Whh1, bih1, bhh1,
                                             x_bf, h1buf, h2buf, out, flags);
  else
    rnn_fused<false><<<128, 128, 0, stream>>>(Wih0, Whh0, bih0, bhh0,
                                              Wih1, Whh1, bih1, bhh1,
                                              x_bf, h1buf, h2buf, out, flags);
}